// Round 13
// baseline (283.231 us; speedup 1.0000x reference)
//
#include <hip/hip_runtime.h>
#include <hip/hip_bf16.h>

typedef short short8 __attribute__((ext_vector_type(8)));
typedef float f32x4 __attribute__((ext_vector_type(4)));

#define B_ 2
#define S_ 2048
#define D_ 1024
#define H_ 16
#define DK_ 64

__device__ inline short f2b(float f) {
  __hip_bfloat16 h = __float2bfloat16(f);
  return *reinterpret_cast<short*>(&h);
}

__device__ inline void load_lds16(const short* g, short* l) {
  __builtin_amdgcn_global_load_lds(
      (const __attribute__((address_space(1))) void*)g,
      (__attribute__((address_space(3))) void*)l, 16, 0, 0);
}

// ------------- weight transpose+convert: Wt[n][k] = bf16(W[k][n]) ----------
__global__ void transpose4_k(const float* __restrict__ w0, const float* __restrict__ w1,
                             const float* __restrict__ w2, const float* __restrict__ w3,
                             short* __restrict__ dst) {
  const float* src = (blockIdx.z == 0) ? w0 : (blockIdx.z == 1) ? w1
                   : (blockIdx.z == 2) ? w2 : w3;
  short* d = dst + (size_t)blockIdx.z * D_ * D_;
  __shared__ float t[32][33];
  int x = blockIdx.x * 32 + threadIdx.x;
  int yb = blockIdx.y * 32;
#pragma unroll
  for (int i = 0; i < 4; i++)
    t[threadIdx.y + i * 8][threadIdx.x] = src[(size_t)(yb + threadIdx.y + i * 8) * D_ + x];
  __syncthreads();
  int x2 = blockIdx.y * 32 + threadIdx.x;
  int y2 = blockIdx.x * 32;
#pragma unroll
  for (int i = 0; i < 4; i++)
    d[(size_t)(y2 + threadIdx.y + i * 8) * D_ + x2] = f2b(t[threadIdx.x][threadIdx.y + i * 8]);
}

// ------------- GEMM core: 128x128 tile, 4 waves (2x2) ----------------------
// NBUF=1: m97 single-buffer (stage; bar; mfma; bar) -> 32KB LDS, 3 blocks/CU.
// NBUF=2: 2-phase double-buffer (for 1-block/CU grids needing intra-block overlap).
// C[m][n] = A[m][:] . Bt[n][:] + bias[n]
// mode 0: fp32 out[m*1024+n];  1: Q scatter *0.125;  2: K scatter;  3: V^T scatter
// LDS[row][s] holds G[row][s ^ (row&7)] (8-elem word granularity, involution).
template <typename AT, int NBUF>
__device__ __forceinline__ void gemm_core(
    const AT* __restrict__ A, const short* __restrict__ Bt,
    const float* __restrict__ bias, short* __restrict__ outS,
    float* __restrict__ outF, int mode,
    short* As, short* Bs, int bm, int bn) {
  const int tid = threadIdx.x;
  const int lane = tid & 63;
  const int wave = tid >> 6;
  const int wm = wave >> 1, wn = wave & 1;
  const int K = D_;

  f32x4 acc[4][4];
#pragma unroll
  for (int i = 0; i < 4; i++)
#pragma unroll
    for (int j = 0; j < 4; j++) acc[i][j] = (f32x4){0.f, 0.f, 0.f, 0.f};

  auto stage = [&](int c, int k0) {
#pragma unroll
    for (int t = 0; t < 4; ++t) {
      int jj = t * 256 + tid;          // 0..1023 chunks of 8 elems
      int row = jj >> 3, slot = jj & 7;
      int sw = ((slot ^ (row & 7)) << 3);
      if constexpr (sizeof(AT) == 4) {
        // fp32 A: reg-stage + convert, swizzled LDS dest
        const float* Ap = &A[(size_t)(bm * 128 + row) * K + k0 + slot * 8];
        float4 a0 = *(const float4*)Ap;
        float4 a1 = *(const float4*)(Ap + 4);
        short8 va;
        va[0] = f2b(a0.x); va[1] = f2b(a0.y); va[2] = f2b(a0.z); va[3] = f2b(a0.w);
        va[4] = f2b(a1.x); va[5] = f2b(a1.y); va[6] = f2b(a1.z); va[7] = f2b(a1.w);
        *(short8*)&As[c * 8192 + row * 64 + sw] = va;
      } else {
        // bf16 A: DMA, linear dest + inverse-swizzled source
        load_lds16(A + (size_t)(bm * 128 + row) * K + k0 + sw, &As[c * 8192 + jj * 8]);
      }
      load_lds16(Bt + (size_t)(bn * 128 + row) * K + k0 + sw, &Bs[c * 8192 + jj * 8]);
    }
  };

  auto compute = [&](int c) {
#pragma unroll
    for (int kk = 0; kk < 2; ++kk) {
      short8 af[4], bf[4];
#pragma unroll
      for (int mi = 0; mi < 4; mi++) {
        int r = wm * 64 + mi * 16 + (lane & 15);
        int slot = kk * 4 + (lane >> 4);
        af[mi] = *(const short8*)&As[c * 8192 + r * 64 + ((slot ^ (r & 7)) << 3)];
      }
#pragma unroll
      for (int ni = 0; ni < 4; ni++) {
        int r = wn * 64 + ni * 16 + (lane & 15);
        int slot = kk * 4 + (lane >> 4);
        bf[ni] = *(const short8*)&Bs[c * 8192 + r * 64 + ((slot ^ (r & 7)) << 3)];
      }
#pragma unroll
      for (int mi = 0; mi < 4; mi++)
#pragma unroll
        for (int ni = 0; ni < 4; ni++)
          acc[mi][ni] = __builtin_amdgcn_mfma_f32_16x16x32_bf16(
              af[mi], bf[ni], acc[mi][ni], 0, 0, 0);
    }
  };

  if constexpr (NBUF == 2) {
    stage(0, 0);
    for (int k0 = 0, it = 0; k0 < K; k0 += 64, ++it) {
      int c = it & 1;
      __syncthreads();                   // drains vmcnt+lgkmcnt: buf c ready
      if (k0 + 64 < K) stage(c ^ 1, k0 + 64);
      compute(c);
    }
  } else {
    for (int k0 = 0; k0 < K; k0 += 64) {
      stage(0, k0);
      __syncthreads();                   // DMA + ds_writes drained: buf ready
      compute(0);
      __syncthreads();                   // all reads done before next overwrite
    }
  }

#pragma unroll
  for (int ni = 0; ni < 4; ni++) {
    int n = bn * 128 + wn * 64 + ni * 16 + (lane & 15);
    float bv = bias[n];
#pragma unroll
    for (int mi = 0; mi < 4; mi++) {
#pragma unroll
      for (int r2 = 0; r2 < 4; r2++) {
        int m = bm * 128 + wm * 64 + mi * 16 + (lane >> 4) * 4 + r2;
        float v = acc[mi][ni][r2] + bv;
        if (mode == 0) {
          outF[(size_t)m * D_ + n] = v;
        } else {
          int b = m >> 11, s = m & 2047, h = n >> 6, dk = n & 63;
          if (mode == 1)
            outS[(((size_t)(b * H_ + h)) * S_ + s) * DK_ + dk] = f2b(v * 0.125f);
          else if (mode == 2)
            outS[(((size_t)(b * H_ + h)) * S_ + s) * DK_ + dk] = f2b(v);
          else
            outS[(((size_t)(b * H_ + h)) * DK_ + dk) * S_ + s] = f2b(v);
        }
      }
    }
  }
}

// XCD-aware decomposition of a flat 256-block grid (32 bm x 8 bn):
// hardware round-robins consecutive ids across 8 XCDs (id & 7). Give XCD g
// the bm-stripe {4g..4g+3} for all bn: per-XCD working set = A-stripe 2MB +
// B 2MB = one L2. A fetched once chip-wide; B once per XCD.
// [R11 measured: FETCH 200MB -> 49MB]
__device__ __forceinline__ void xcd_map(int f, int& bm, int& bn) {
  int xcd = f & 7;
  int w = f >> 3;          // 0..31
  bn = w & 7;
  bm = xcd * 4 + (w >> 3); // 0..31
}

__global__ __launch_bounds__(256) void proj3_k(
    const float* __restrict__ q, const float* __restrict__ k,
    const float* __restrict__ v, const short* __restrict__ wt,
    const float* __restrict__ bq, const float* __restrict__ bk,
    const float* __restrict__ bv,
    short* __restrict__ Qb, short* __restrict__ Kb, short* __restrict__ Vtb) {
  __shared__ short As[8192];           // single-buffered: 32KB total
  __shared__ short Bs[8192];
  int z = blockIdx.z;
  const float* A = (z == 0) ? q : (z == 1) ? k : v;
  const short* Bt = wt + (size_t)z * D_ * D_;
  const float* bias = (z == 0) ? bq : (z == 1) ? bk : bv;
  short* out = (z == 0) ? Qb : (z == 1) ? Kb : Vtb;
  int bm, bn;
  xcd_map(blockIdx.x + 8 * blockIdx.y, bm, bn);
  gemm_core<float, 1>(A, Bt, bias, out, nullptr, z + 1, As, Bs, bm, bn);
}

__global__ __launch_bounds__(256) void gemm_final_k(
    const short* __restrict__ Xb, const short* __restrict__ wt,
    const float* __restrict__ bo, float* __restrict__ out) {
  __shared__ short As[2 * 8192];       // 1 block/CU grid: keep intra-block dbuf
  __shared__ short Bs[2 * 8192];
  int bm, bn;
  xcd_map(blockIdx.x + 8 * blockIdx.y, bm, bn);
  gemm_core<short, 2>(Xb, wt, bo, nullptr, out, 0, As, Bs, bm, bn);
}

// ---------------- causal flash attention, LDS-staged K/V, 2-phase -----------
// Q: [B*H][S][DK] bf16 (pre-scaled 1/8), K: [B*H][S][DK], Vt: [B*H][DK][S]
__global__ __launch_bounds__(256) void attn_k(
    const short* __restrict__ Q, const short* __restrict__ Kg,
    const short* __restrict__ Vt, short* __restrict__ X) {
  // XCD-chunked bh (4 heads per XCD) + big-qb-first for tail balance
  const int id = blockIdx.x + 32 * blockIdx.y;     // 0..1023
  const int bh = (id & 7) * 4 + ((id >> 3) & 3);   // bijective
  const int qb = 31 - (id >> 5);
  const int tid = threadIdx.x;
  const int lane = tid & 63;
  const int wave = tid >> 6;

  const short* Qh = Q + (size_t)bh * S_ * DK_;
  const short* Kh = Kg + (size_t)bh * S_ * DK_;
  const short* Vh = Vt + (size_t)bh * DK_ * S_;

  __shared__ short Ks[2][4096];        // [kv 64][dk 64] swizzled
  __shared__ short Vs[2][4096];        // [dk 64][kv 64] swizzled
  __shared__ short Plds[4][1024];      // per-wave 16x64, swizzled

  auto stage = [&](int c, int jt) {
#pragma unroll
    for (int t = 0; t < 2; ++t) {
      int jj = t * 256 + tid;          // 0..511
      int row = jj >> 3, slot = jj & 7;
      int sw = ((slot ^ (row & 7)) << 3);
      load_lds16(Kh + (size_t)(jt * 64 + row) * DK_ + sw, &Ks[c][jj * 8]);
      load_lds16(Vh + (size_t)row * S_ + jt * 64 + sw, &Vs[c][jj * 8]);
    }
  };

  const int qrow0 = qb * 64 + wave * 16;
  short8 qf[2];
#pragma unroll
  for (int kk = 0; kk < 2; kk++)
    qf[kk] = *(const short8*)&Qh[(size_t)(qrow0 + (lane & 15)) * DK_ + kk * 32 + (lane >> 4) * 8];

  float m_run[4], l_run[4];
  f32x4 oacc[4];
#pragma unroll
  for (int r = 0; r < 4; r++) { m_run[r] = -1e30f; l_run[r] = 0.f; }
#pragma unroll
  for (int ni = 0; ni < 4; ni++) oacc[ni] = (f32x4){0.f, 0.f, 0.f, 0.f};

  stage(0, 0);
  for (int j = 0; j <= qb; j++) {
    int c = j & 1;
    __syncthreads();                   // buf c ready (drains vmcnt)
    if (j < qb) stage(c ^ 1, j + 1);   // prefetch next tile

    f32x4 sacc[4];
#pragma unroll
    for (int ni = 0; ni < 4; ni++) sacc[ni] = (f32x4){0.f, 0.f, 0.f, 0.f};
#pragma unroll
    for (int kk = 0; kk < 2; kk++) {
#pragma unroll
      for (int ni = 0; ni < 4; ni++) {
        int r = ni * 16 + (lane & 15);
        int slot = kk * 4 + (lane >> 4);
        short8 kf = *(const short8*)&Ks[c][r * 64 + ((slot ^ (r & 7)) << 3)];
        sacc[ni] = __builtin_amdgcn_mfma_f32_16x16x32_bf16(qf[kk], kf, sacc[ni], 0, 0, 0);
      }
    }
    if (j == qb) {  // causal diagonal tile
#pragma unroll
      for (int ni = 0; ni < 4; ni++)
#pragma unroll
        for (int r = 0; r < 4; r++) {
          int col = j * 64 + ni * 16 + (lane & 15);
          int row = qrow0 + (lane >> 4) * 4 + r;
          if (col > row) sacc[ni][r] = -1e30f;
        }
    }
    // online softmax per row (rows live on 16-lane groups)
    float p[4][4];
#pragma unroll
    for (int r = 0; r < 4; r++) {
      float mx = fmaxf(fmaxf(sacc[0][r], sacc[1][r]), fmaxf(sacc[2][r], sacc[3][r]));
#pragma unroll
      for (int m2 = 1; m2 < 16; m2 <<= 1) mx = fmaxf(mx, __shfl_xor(mx, m2, 64));
      float mnew = fmaxf(m_run[r], mx);
      float scl = __expf(m_run[r] - mnew);
      float rs = 0.f;
#pragma unroll
      for (int ni = 0; ni < 4; ni++) {
        float e = __expf(sacc[ni][r] - mnew);
        p[ni][r] = e; rs += e;
      }
#pragma unroll
      for (int m2 = 1; m2 < 16; m2 <<= 1) rs += __shfl_xor(rs, m2, 64);
      l_run[r] = l_run[r] * scl + rs;
      m_run[r] = mnew;
#pragma unroll
      for (int ni = 0; ni < 4; ni++) oacc[ni][r] *= scl;
    }
    // P -> wave-private LDS (C-layout -> A-layout), swizzled
#pragma unroll
    for (int ni = 0; ni < 4; ni++)
#pragma unroll
      for (int r = 0; r < 4; r++) {
        int row = (lane >> 4) * 4 + r;
        int col = ni * 16 + (lane & 15);
        int slot = col >> 3, win = col & 7;
        Plds[wave][row * 64 + ((slot ^ (row & 7)) << 3) + win] = f2b(p[ni][r]);
      }
    // intra-wave ordering only (Plds is wave-private): wait DS writes, then
    // fence the scheduler so the b128 reads below can't hoist above.
    asm volatile("s_waitcnt lgkmcnt(0)" ::: "memory");
    __builtin_amdgcn_sched_barrier(0);
    // PV from Plds + Vs[c]
#pragma unroll
    for (int kk2 = 0; kk2 < 2; kk2++) {
      int prow = lane & 15;
      int pslot = kk2 * 4 + (lane >> 4);
      short8 pf = *(const short8*)&Plds[wave][prow * 64 + ((pslot ^ (prow & 7)) << 3)];
#pragma unroll
      for (int ni = 0; ni < 4; ni++) {
        int vr = ni * 16 + (lane & 15);
        int vslot = kk2 * 4 + (lane >> 4);
        short8 vf = *(const short8*)&Vs[c][vr * 64 + ((vslot ^ (vr & 7)) << 3)];
        oacc[ni] = __builtin_amdgcn_mfma_f32_16x16x32_bf16(pf, vf, oacc[ni], 0, 0, 0);
      }
    }
  }

  const int b = bh >> 4, h = bh & 15;
#pragma unroll
  for (int r = 0; r < 4; r++) {
    float inv = 1.f / l_run[r];
    int s = qrow0 + (lane >> 4) * 4 + r;
#pragma unroll
    for (int ni = 0; ni < 4; ni++) {
      int dk = ni * 16 + (lane & 15);
      X[((size_t)(b * S_ + s)) * D_ + h * DK_ + dk] = f2b(oacc[ni][r] * inv);
    }
  }
}

extern "C" void kernel_launch(void* const* d_in, const int* in_sizes, int n_in,
                              void* d_out, int out_size, void* d_ws, size_t ws_size,
                              hipStream_t stream) {
  const float* query  = (const float*)d_in[0];
  const float* key_in = (const float*)d_in[1];
  const float* value  = (const float*)d_in[2];
  // d_in[3] = mask: causal, applied statically
  const float* Wq = (const float*)d_in[4];
  const float* bq = (const float*)d_in[5];
  const float* Wk = (const float*)d_in[6];
  const float* bk = (const float*)d_in[7];
  const float* Wv = (const float*)d_in[8];
  const float* bv = (const float*)d_in[9];
  const float* Wo = (const float*)d_in[10];
  const float* bo = (const float*)d_in[11];
  float* out = (float*)d_out;   // fp32 output per reference dtype

  char* ws = (char*)d_ws;
  short* wt  = (short*)(ws);                    // 4 x [1024][1024] bf16 = 8 MiB
  short* Qb  = (short*)(ws + (8ull  << 20));    // [B*H][S][DK] bf16 8 MiB
  short* Kb  = (short*)(ws + (16ull << 20));    // [B*H][S][DK] bf16 8 MiB
  short* Vtb = (short*)(ws + (24ull << 20));    // [B*H][DK][S] bf16 8 MiB
  short* Xb  = (short*)(ws + (32ull << 20));    // [B][S][D]    bf16 8 MiB

  transpose4_k<<<dim3(32, 32, 4), dim3(32, 8), 0, stream>>>(Wq, Wk, Wv, Wo, wt);

  proj3_k<<<dim3(8, 32, 3), 256, 0, stream>>>(query, key_in, value, wt,
                                              bq, bk, bv, Qb, Kb, Vtb);

  attn_k<<<dim3(32, 32), 256, 0, stream>>>(Qb, Kb, Vtb, Xb);

  gemm_final_k<<<dim3(8, 32), 256, 0, stream>>>(Xb, wt + 3ull * D_ * D_, bo, out);
}

// Round 14
// 267.362 us; speedup vs baseline: 1.0594x; 1.0594x over previous
//
#include <hip/hip_runtime.h>
#include <hip/hip_bf16.h>

typedef short short8 __attribute__((ext_vector_type(8)));
typedef float f32x4 __attribute__((ext_vector_type(4)));

#define B_ 2
#define S_ 2048
#define D_ 1024
#define H_ 16
#define DK_ 64

__device__ inline short f2b(float f) {
  __hip_bfloat16 h = __float2bfloat16(f);
  return *reinterpret_cast<short*>(&h);
}

__device__ inline void load_lds16(const short* g, short* l) {
  __builtin_amdgcn_global_load_lds(
      (const __attribute__((address_space(1))) void*)g,
      (__attribute__((address_space(3))) void*)l, 16, 0, 0);
}

// ------------- weight transpose+convert: Wt[n][k] = bf16(W[k][n]) ----------
__global__ void transpose4_k(const float* __restrict__ w0, const float* __restrict__ w1,
                             const float* __restrict__ w2, const float* __restrict__ w3,
                             short* __restrict__ dst) {
  const float* src = (blockIdx.z == 0) ? w0 : (blockIdx.z == 1) ? w1
                   : (blockIdx.z == 2) ? w2 : w3;
  short* d = dst + (size_t)blockIdx.z * D_ * D_;
  __shared__ float t[32][33];
  int x = blockIdx.x * 32 + threadIdx.x;
  int yb = blockIdx.y * 32;
#pragma unroll
  for (int i = 0; i < 4; i++)
    t[threadIdx.y + i * 8][threadIdx.x] = src[(size_t)(yb + threadIdx.y + i * 8) * D_ + x];
  __syncthreads();
  int x2 = blockIdx.y * 32 + threadIdx.x;
  int y2 = blockIdx.x * 32;
#pragma unroll
  for (int i = 0; i < 4; i++)
    d[(size_t)(y2 + threadIdx.y + i * 8) * D_ + x2] = f2b(t[threadIdx.x][threadIdx.y + i * 8]);
}

// ------------- GEMM core: 128x128 tile, 8 waves (2x4), 2-phase dbuf ---------
// 512 threads: 16 resident waves/CU at 2 blocks/CU (R13 lesson: dbuf is load-
// bearing; more waves, not fewer buffers, is the latency-hiding lever).
// C[m][n] = A[m][:] . Bt[n][:] + bias[n]
// mode 0: fp32 out[m*1024+n];  1: Q scatter *0.125;  2: K scatter;  3: V^T scatter
// LDS[row][s] holds G[row][s ^ (row&7)] (8-elem word granularity, involution).
template <typename AT>
__device__ __forceinline__ void gemm_core(
    const AT* __restrict__ A, const short* __restrict__ Bt,
    const float* __restrict__ bias, short* __restrict__ outS,
    float* __restrict__ outF, int mode,
    short* As, short* Bs, int bm, int bn) {
  const int tid = threadIdx.x;         // 0..511
  const int lane = tid & 63;
  const int wave = tid >> 6;           // 0..7
  const int wm = wave >> 2, wn = wave & 3;   // 2 x 4 wave grid
  const int K = D_;

  f32x4 acc[4][2];
#pragma unroll
  for (int i = 0; i < 4; i++)
#pragma unroll
    for (int j = 0; j < 2; j++) acc[i][j] = (f32x4){0.f, 0.f, 0.f, 0.f};

  auto stage = [&](int c, int k0) {
#pragma unroll
    for (int t = 0; t < 2; ++t) {
      int jj = t * 512 + tid;          // 0..1023 chunks of 8 elems
      int row = jj >> 3, slot = jj & 7;
      int sw = ((slot ^ (row & 7)) << 3);
      if constexpr (sizeof(AT) == 4) {
        // fp32 A: reg-stage + convert, swizzled LDS dest
        const float* Ap = &A[(size_t)(bm * 128 + row) * K + k0 + slot * 8];
        float4 a0 = *(const float4*)Ap;
        float4 a1 = *(const float4*)(Ap + 4);
        short8 va;
        va[0] = f2b(a0.x); va[1] = f2b(a0.y); va[2] = f2b(a0.z); va[3] = f2b(a0.w);
        va[4] = f2b(a1.x); va[5] = f2b(a1.y); va[6] = f2b(a1.z); va[7] = f2b(a1.w);
        *(short8*)&As[c * 8192 + row * 64 + sw] = va;
      } else {
        // bf16 A: DMA, linear dest + inverse-swizzled source
        load_lds16(A + (size_t)(bm * 128 + row) * K + k0 + sw, &As[c * 8192 + jj * 8]);
      }
      load_lds16(Bt + (size_t)(bn * 128 + row) * K + k0 + sw, &Bs[c * 8192 + jj * 8]);
    }
  };

  auto compute = [&](int c) {
#pragma unroll
    for (int kk = 0; kk < 2; ++kk) {
      short8 af[4], bf[2];
#pragma unroll
      for (int mi = 0; mi < 4; mi++) {
        int r = wm * 64 + mi * 16 + (lane & 15);
        int slot = kk * 4 + (lane >> 4);
        af[mi] = *(const short8*)&As[c * 8192 + r * 64 + ((slot ^ (r & 7)) << 3)];
      }
#pragma unroll
      for (int ni = 0; ni < 2; ni++) {
        int r = wn * 32 + ni * 16 + (lane & 15);
        int slot = kk * 4 + (lane >> 4);
        bf[ni] = *(const short8*)&Bs[c * 8192 + r * 64 + ((slot ^ (r & 7)) << 3)];
      }
#pragma unroll
      for (int mi = 0; mi < 4; mi++)
#pragma unroll
        for (int ni = 0; ni < 2; ni++)
          acc[mi][ni] = __builtin_amdgcn_mfma_f32_16x16x32_bf16(
              af[mi], bf[ni], acc[mi][ni], 0, 0, 0);
    }
  };

  stage(0, 0);
  for (int k0 = 0, it = 0; k0 < K; k0 += 64, ++it) {
    int c = it & 1;
    __syncthreads();                   // drains vmcnt+lgkmcnt: buf c ready
    if (k0 + 64 < K) stage(c ^ 1, k0 + 64);
    compute(c);
  }

#pragma unroll
  for (int ni = 0; ni < 2; ni++) {
    int n = bn * 128 + wn * 32 + ni * 16 + (lane & 15);
    float bv = bias[n];
#pragma unroll
    for (int mi = 0; mi < 4; mi++) {
#pragma unroll
      for (int r2 = 0; r2 < 4; r2++) {
        int m = bm * 128 + wm * 64 + mi * 16 + (lane >> 4) * 4 + r2;
        float v = acc[mi][ni][r2] + bv;
        if (mode == 0) {
          outF[(size_t)m * D_ + n] = v;
        } else {
          int b = m >> 11, s = m & 2047, h = n >> 6, dk = n & 63;
          if (mode == 1)
            outS[(((size_t)(b * H_ + h)) * S_ + s) * DK_ + dk] = f2b(v * 0.125f);
          else if (mode == 2)
            outS[(((size_t)(b * H_ + h)) * S_ + s) * DK_ + dk] = f2b(v);
          else
            outS[(((size_t)(b * H_ + h)) * DK_ + dk) * S_ + s] = f2b(v);
        }
      }
    }
  }
}

// XCD-aware decomposition of a flat 256-block grid (32 bm x 8 bn):
// XCD g owns bm-stripe {4g..4g+3} for all bn -> per-XCD set fits one L2.
// [R11 measured: FETCH 200MB -> 49MB = fp32-A compulsory minimum]
__device__ __forceinline__ void xcd_map(int f, int& bm, int& bn) {
  int xcd = f & 7;
  int w = f >> 3;          // 0..31
  bn = w & 7;
  bm = xcd * 4 + (w >> 3); // 0..31
}

__global__ __launch_bounds__(512) void proj3_k(
    const float* __restrict__ q, const float* __restrict__ k,
    const float* __restrict__ v, const short* __restrict__ wt,
    const float* __restrict__ bq, const float* __restrict__ bk,
    const float* __restrict__ bv,
    short* __restrict__ Qb, short* __restrict__ Kb, short* __restrict__ Vtb) {
  __shared__ short As[2 * 8192];
  __shared__ short Bs[2 * 8192];
  int z = blockIdx.z;
  const float* A = (z == 0) ? q : (z == 1) ? k : v;
  const short* Bt = wt + (size_t)z * D_ * D_;
  const float* bias = (z == 0) ? bq : (z == 1) ? bk : bv;
  short* out = (z == 0) ? Qb : (z == 1) ? Kb : Vtb;
  int bm, bn;
  xcd_map(blockIdx.x + 8 * blockIdx.y, bm, bn);
  gemm_core<float>(A, Bt, bias, out, nullptr, z + 1, As, Bs, bm, bn);
}

__global__ __launch_bounds__(512) void gemm_final_k(
    const short* __restrict__ Xb, const short* __restrict__ wt,
    const float* __restrict__ bo, float* __restrict__ out) {
  __shared__ short As[2 * 8192];
  __shared__ short Bs[2 * 8192];
  int bm, bn;
  xcd_map(blockIdx.x + 8 * blockIdx.y, bm, bn);
  gemm_core<short>(Xb, wt, bo, nullptr, out, 0, As, Bs, bm, bn);
}

// ---------------- causal flash attention, LDS-staged K/V, 2-phase -----------
// Q: [B*H][S][DK] bf16 (pre-scaled 1/8), K: [B*H][S][DK], Vt: [B*H][DK][S]
__global__ __launch_bounds__(256) void attn_k(
    const short* __restrict__ Q, const short* __restrict__ Kg,
    const short* __restrict__ Vt, short* __restrict__ X) {
  // XCD-chunked bh (4 heads per XCD) + big-qb-first for tail balance
  const int id = blockIdx.x + 32 * blockIdx.y;     // 0..1023
  const int bh = (id & 7) * 4 + ((id >> 3) & 3);   // bijective
  const int qb = 31 - (id >> 5);
  const int tid = threadIdx.x;
  const int lane = tid & 63;
  const int wave = tid >> 6;

  const short* Qh = Q + (size_t)bh * S_ * DK_;
  const short* Kh = Kg + (size_t)bh * S_ * DK_;
  const short* Vh = Vt + (size_t)bh * DK_ * S_;

  __shared__ short Ks[2][4096];        // [kv 64][dk 64] swizzled
  __shared__ short Vs[2][4096];        // [dk 64][kv 64] swizzled
  __shared__ short Plds[4][1024];      // per-wave 16x64, swizzled

  auto stage = [&](int c, int jt) {
#pragma unroll
    for (int t = 0; t < 2; ++t) {
      int jj = t * 256 + tid;          // 0..511
      int row = jj >> 3, slot = jj & 7;
      int sw = ((slot ^ (row & 7)) << 3);
      load_lds16(Kh + (size_t)(jt * 64 + row) * DK_ + sw, &Ks[c][jj * 8]);
      load_lds16(Vh + (size_t)row * S_ + jt * 64 + sw, &Vs[c][jj * 8]);
    }
  };

  const int qrow0 = qb * 64 + wave * 16;
  short8 qf[2];
#pragma unroll
  for (int kk = 0; kk < 2; kk++)
    qf[kk] = *(const short8*)&Qh[(size_t)(qrow0 + (lane & 15)) * DK_ + kk * 32 + (lane >> 4) * 8];

  float m_run[4], l_run[4];
  f32x4 oacc[4];
#pragma unroll
  for (int r = 0; r < 4; r++) { m_run[r] = -1e30f; l_run[r] = 0.f; }
#pragma unroll
  for (int ni = 0; ni < 4; ni++) oacc[ni] = (f32x4){0.f, 0.f, 0.f, 0.f};

  stage(0, 0);
  for (int j = 0; j <= qb; j++) {
    int c = j & 1;
    __syncthreads();                   // buf c ready (drains vmcnt)
    if (j < qb) stage(c ^ 1, j + 1);   // prefetch next tile

    f32x4 sacc[4];
#pragma unroll
    for (int ni = 0; ni < 4; ni++) sacc[ni] = (f32x4){0.f, 0.f, 0.f, 0.f};
#pragma unroll
    for (int kk = 0; kk < 2; kk++) {
#pragma unroll
      for (int ni = 0; ni < 4; ni++) {
        int r = ni * 16 + (lane & 15);
        int slot = kk * 4 + (lane >> 4);
        short8 kf = *(const short8*)&Ks[c][r * 64 + ((slot ^ (r & 7)) << 3)];
        sacc[ni] = __builtin_amdgcn_mfma_f32_16x16x32_bf16(qf[kk], kf, sacc[ni], 0, 0, 0);
      }
    }
    if (j == qb) {  // causal diagonal tile
#pragma unroll
      for (int ni = 0; ni < 4; ni++)
#pragma unroll
        for (int r = 0; r < 4; r++) {
          int col = j * 64 + ni * 16 + (lane & 15);
          int row = qrow0 + (lane >> 4) * 4 + r;
          if (col > row) sacc[ni][r] = -1e30f;
        }
    }
    // online softmax per row (rows live on 16-lane groups)
    float p[4][4];
#pragma unroll
    for (int r = 0; r < 4; r++) {
      float mx = fmaxf(fmaxf(sacc[0][r], sacc[1][r]), fmaxf(sacc[2][r], sacc[3][r]));
#pragma unroll
      for (int m2 = 1; m2 < 16; m2 <<= 1) mx = fmaxf(mx, __shfl_xor(mx, m2, 64));
      float mnew = fmaxf(m_run[r], mx);
      float scl = __expf(m_run[r] - mnew);
      float rs = 0.f;
#pragma unroll
      for (int ni = 0; ni < 4; ni++) {
        float e = __expf(sacc[ni][r] - mnew);
        p[ni][r] = e; rs += e;
      }
#pragma unroll
      for (int m2 = 1; m2 < 16; m2 <<= 1) rs += __shfl_xor(rs, m2, 64);
      l_run[r] = l_run[r] * scl + rs;
      m_run[r] = mnew;
#pragma unroll
      for (int ni = 0; ni < 4; ni++) oacc[ni][r] *= scl;
    }
    // P -> wave-private LDS (C-layout -> A-layout), swizzled
#pragma unroll
    for (int ni = 0; ni < 4; ni++)
#pragma unroll
      for (int r = 0; r < 4; r++) {
        int row = (lane >> 4) * 4 + r;
        int col = ni * 16 + (lane & 15);
        int slot = col >> 3, win = col & 7;
        Plds[wave][row * 64 + ((slot ^ (row & 7)) << 3) + win] = f2b(p[ni][r]);
      }
    // intra-wave ordering only (Plds is wave-private): wait DS writes, then
    // fence the scheduler so the b128 reads below can't hoist above.
    asm volatile("s_waitcnt lgkmcnt(0)" ::: "memory");
    __builtin_amdgcn_sched_barrier(0);
    // PV from Plds + Vs[c]
#pragma unroll
    for (int kk2 = 0; kk2 < 2; kk2++) {
      int prow = lane & 15;
      int pslot = kk2 * 4 + (lane >> 4);
      short8 pf = *(const short8*)&Plds[wave][prow * 64 + ((pslot ^ (prow & 7)) << 3)];
#pragma unroll
      for (int ni = 0; ni < 4; ni++) {
        int vr = ni * 16 + (lane & 15);
        int vslot = kk2 * 4 + (lane >> 4);
        short8 vf = *(const short8*)&Vs[c][vr * 64 + ((vslot ^ (vr & 7)) << 3)];
        oacc[ni] = __builtin_amdgcn_mfma_f32_16x16x32_bf16(pf, vf, oacc[ni], 0, 0, 0);
      }
    }
  }

  const int b = bh >> 4, h = bh & 15;
#pragma unroll
  for (int r = 0; r < 4; r++) {
    float inv = 1.f / l_run[r];
    int s = qrow0 + (lane >> 4) * 4 + r;
#pragma unroll
    for (int ni = 0; ni < 4; ni++) {
      int dk = ni * 16 + (lane & 15);
      X[((size_t)(b * S_ + s)) * D_ + h * DK_ + dk] = f2b(oacc[ni][r] * inv);
    }
  }
}

extern "C" void kernel_launch(void* const* d_in, const int* in_sizes, int n_in,
                              void* d_out, int out_size, void* d_ws, size_t ws_size,
                              hipStream_t stream) {
  const float* query  = (const float*)d_in[0];
  const float* key_in = (const float*)d_in[1];
  const float* value  = (const float*)d_in[2];
  // d_in[3] = mask: causal, applied statically
  const float* Wq = (const float*)d_in[4];
  const float* bq = (const float*)d_in[5];
  const float* Wk = (const float*)d_in[6];
  const float* bk = (const float*)d_in[7];
  const float* Wv = (const float*)d_in[8];
  const float* bv = (const float*)d_in[9];
  const float* Wo = (const float*)d_in[10];
  const float* bo = (const float*)d_in[11];
  float* out = (float*)d_out;   // fp32 output per reference dtype

  char* ws = (char*)d_ws;
  short* wt  = (short*)(ws);                    // 4 x [1024][1024] bf16 = 8 MiB
  short* Qb  = (short*)(ws + (8ull  << 20));    // [B*H][S][DK] bf16 8 MiB
  short* Kb  = (short*)(ws + (16ull << 20));    // [B*H][S][DK] bf16 8 MiB
  short* Vtb = (short*)(ws + (24ull << 20));    // [B*H][DK][S] bf16 8 MiB
  short* Xb  = (short*)(ws + (32ull << 20));    // [B][S][D]    bf16 8 MiB

  transpose4_k<<<dim3(32, 32, 4), dim3(32, 8), 0, stream>>>(Wq, Wk, Wv, Wo, wt);

  proj3_k<<<dim3(8, 32, 3), 512, 0, stream>>>(query, key_in, value, wt,
                                              bq, bk, bv, Qb, Kb, Vtb);

  attn_k<<<dim3(32, 32), 256, 0, stream>>>(Qb, Kb, Vtb, Xb);

  gemm_final_k<<<dim3(8, 32), 512, 0, stream>>>(Xb, wt + 3ull * D_ * D_, bo, out);
}